// Round 9
// baseline (128.381 us; speedup 1.0000x reference)
//
#include <hip/hip_runtime.h>
#include <hip/hip_bf16.h>
#include <math.h>

static constexpr int NNODES = 50000;
static constexpr int NEDGES = 800000;
static constexpr int NBUCK = (NNODES + 255) >> 8;  // 196 buckets of 256 dst nodes
static constexpr int MAXB = 6144;  // max edges/bucket (mean 4096 for uniform random)

typedef __attribute__((ext_vector_type(8))) short bf16x8;
typedef __attribute__((ext_vector_type(4))) float f32x4;

__device__ inline short f2bf(float f) {
  union { __hip_bfloat16 h; short s; } u;
  u.h = __float2bfloat16(f);
  return u.s;
}

__device__ inline float bf2f(short s) {
  union { unsigned int u; float f; } u;
  u.u = ((unsigned int)(unsigned short)s) << 16;
  return u.f;
}

// ---------------- bucketed CSR build ----------------
// binned entry: int2 { (dst_local<<16) | src , float_bits(w) }  (src < 2^16, dl < 2^8)

__global__ void initcur_kernel(int* __restrict__ gcur) {
  int b = threadIdx.x;
  if (b < NBUCK) gcur[b] = b * MAXB;
}

// bin 2048 edges/WG into per-bucket regions. Per-WG LDS histogram -> ONE global
// atomic per (WG, bucket) -> contiguous run reservation -> direct int2 writes.
__global__ __launch_bounds__(256) void bin_kernel(const int* __restrict__ row,
                                                  const int* __restrict__ col,
                                                  const float* __restrict__ w,
                                                  int* __restrict__ gcur,
                                                  int2* __restrict__ binned, int e_cnt) {
  __shared__ int rcnt[NBUCK];
  __shared__ int rcur[NBUCK];
  __shared__ int gbase[NBUCK];
  const int tid = threadIdx.x;
  for (int b = tid; b < NBUCK; b += 256) {
    rcnt[b] = 0;
    rcur[b] = 0;
  }
  __syncthreads();
  const int base = blockIdx.x * 2048;
  int srcs[8], dsts[8];
  float ws_[8];
#pragma unroll
  for (int j = 0; j < 8; ++j) {
    int idx = base + tid + 256 * j;
    if (idx < e_cnt) {
      srcs[j] = row[idx];
      dsts[j] = col[idx];
      ws_[j] = w[idx];
      atomicAdd(&rcnt[dsts[j] >> 8], 1);
    } else {
      dsts[j] = -1;
    }
  }
  __syncthreads();
  for (int b = tid; b < NBUCK; b += 256)
    if (rcnt[b] > 0) gbase[b] = atomicAdd(&gcur[b], rcnt[b]);
  __syncthreads();
#pragma unroll
  for (int j = 0; j < 8; ++j) {
    if (dsts[j] >= 0) {
      int b = dsts[j] >> 8;
      int dl = dsts[j] & 255;
      int pos = gbase[b] + atomicAdd(&rcur[b], 1);
      binned[pos] = make_int2((dl << 16) | srcs[j], __float_as_int(ws_[j]));
    }
  }
}

// per-bucket deg (LDS f32 atomics) + cnt; coalesced dinv/cntg writes
__global__ __launch_bounds__(256) void bdeg_kernel(const int2* __restrict__ binned,
                                                   const int* __restrict__ gcur,
                                                   float* __restrict__ dinv,
                                                   int* __restrict__ cntg, int n) {
  __shared__ float degf[256];
  __shared__ int cnt[256];
  const int b = blockIdx.x, tid = threadIdx.x;
  degf[tid] = 0.f;
  cnt[tid] = 0;
  __syncthreads();
  const int bcnt = gcur[b] - b * MAXB;
  const int2* bp = binned + (size_t)b * MAXB;
  for (int i = tid; i < bcnt; i += 256) {
    int2 e = bp[i];
    int dl = (e.x >> 16) & 255;
    atomicAdd(&degf[dl], __int_as_float(e.y));
    atomicAdd(&cnt[dl], 1);
  }
  __syncthreads();
  int node = b * 256 + tid;
  if (node < n) {
    dinv[node] = 1.0f / sqrtf(degf[tid] + 1.0f);  // self-loop weight 1.0
    cntg[node] = cnt[tid];
  }
}

// exclusive scan of the 196 bucket counts (single WG)
__global__ void bscan_kernel(const int* __restrict__ gcur, int* __restrict__ bbase) {
  __shared__ int buf[256];
  int tid = threadIdx.x;
  int v = (tid < NBUCK) ? gcur[tid] - tid * MAXB : 0;
  buf[tid] = v;
  __syncthreads();
  for (int off = 1; off < 256; off <<= 1) {
    int t = (tid >= off) ? buf[tid - off] : 0;
    __syncthreads();
    buf[tid] += t;
    __syncthreads();
  }
  if (tid < NBUCK) bbase[tid] = buf[tid] - v;
}

// per-bucket: local scan -> start[]; norm + CSR fill via LDS cursors.
__global__ __launch_bounds__(256) void csrfill_kernel(
    const int2* __restrict__ binned, const int* __restrict__ gcur,
    const int* __restrict__ bbase, const float* __restrict__ dinv,
    const int* __restrict__ cntg, int* __restrict__ start, int2* __restrict__ csr, int n) {
  __shared__ float dvL[256];
  __shared__ int cur[256];
  __shared__ int buf[256];
  const int b = blockIdx.x, tid = threadIdx.x;
  const int node = b * 256 + tid;
  int c = (node < n) ? cntg[node] : 0;
  dvL[tid] = (node < n) ? dinv[node] : 0.f;
  buf[tid] = c;
  __syncthreads();
  for (int off = 1; off < 256; off <<= 1) {
    int t = (tid >= off) ? buf[tid - off] : 0;
    __syncthreads();
    buf[tid] += t;
    __syncthreads();
  }
  int localstart = buf[tid] - c;
  const int gb = bbase[b];
  if (node < n) start[node] = gb + localstart;
  cur[tid] = localstart;
  __syncthreads();
  const int bcnt = gcur[b] - b * MAXB;
  const int2* bp = binned + (size_t)b * MAXB;
  for (int i = tid; i < bcnt; i += 256) {
    int2 e = bp[i];
    int src = e.x & 0xFFFF;
    int dl = (e.x >> 16) & 255;
    float nrm = dinv[src] * __int_as_float(e.y) * dvL[dl];
    int pos = gb + atomicAdd(&cur[dl], 1);
    csr[pos] = make_int2(src, __float_as_int(nrm));
  }
}

// ---------------- W pre-pack: fragment-major bf16 (one-time, tiny) ----------------
// Fragment f = kf*NPF + nfb; lane l holds W[kf*32 + (l>>4)*8 + i][nfb*16 + (l&15)], i=0..7.

template <int K, int NTOT>
__global__ void packW_kernel(const float* __restrict__ W, short* __restrict__ Wpk) {
  constexpr int KF = K / 32;
  constexpr int NPF = NTOT / 16;
  int t = blockIdx.x * 256 + threadIdx.x;
  if (t >= KF * NPF * 64) return;
  int f = t >> 6, l = t & 63;
  int kf = f / NPF, nfb = f % NPF;
  int col = nfb * 16 + (l & 15);
  int krow = kf * 32 + (l >> 4) * 8;
  bf16x8 bv;
#pragma unroll
  for (int i = 0; i < 8; ++i) bv[i] = f2bf(W[(size_t)(krow + i) * NTOT + col]);
  ((bf16x8*)Wpk)[t] = bv;
}

// ---------------- bf16 MFMA GEMM: H = A @ W, W pre-packed, LDS-staged ----------------
// Block: 256 threads = 4 waves (2M x 2N). Block tile = 128 rows x NTOT cols.
// Wpk staged to LDS via coalesced int4 copies (fragment-major already);
// K-loop reads B via conflict-free ds_read_b128.
// D layout col=lane&15, row=(lane>>4)*4+reg [m89-verified].

template <int K, int NTOT, bool A_BF16>
__global__ __launch_bounds__(256) void mfma_gemm_kernel(const void* __restrict__ Av,
                                                        const short* __restrict__ Wpk,
                                                        short* __restrict__ H, int n) {
  constexpr int KF = K / 32;
  constexpr int NPF = NTOT / 16;
  constexpr int NF = NTOT / 32;
  constexpr int NCHUNK = KF * NPF * 64 * 16 / 16 / 256;  // int4 copies per thread
  __shared__ alignas(16) short Blds[KF * NPF * 64 * 8];
  const int tid = threadIdx.x;
  const int lane = tid & 63;
  const int wave = tid >> 6;
  const int lrow = lane & 15;
  const int lgrp = lane >> 4;

  {
    const int4* srcp = (const int4*)Wpk;
    int4* dstp = (int4*)Blds;
#pragma unroll
    for (int j = 0; j < NCHUNK; ++j) dstp[j * 256 + tid] = srcp[j * 256 + tid];
  }
  __syncthreads();

  const int wm = wave >> 1, wn = wave & 1;
  const int rowbase = blockIdx.x * 128 + wm * 64;
  const int nmax = n - 1;
  f32x4 acc[4][NF] = {};

  for (int ks = 0; ks < KF; ++ks) {
    bf16x8 af[4];
#pragma unroll
    for (int mi = 0; mi < 4; ++mi) {
      int r = rowbase + mi * 16 + lrow;
      r = r > nmax ? nmax : r;
      if (A_BF16) {
        const short* X = (const short*)Av;
        af[mi] = *(const bf16x8*)(X + (size_t)r * K + ks * 32 + lgrp * 8);
      } else {
        const float* X = (const float*)Av;
        const float* xp = X + (size_t)r * K + ks * 32 + lgrp * 8;
        float4 x0 = *(const float4*)xp;
        float4 x1 = *(const float4*)(xp + 4);
        af[mi][0] = f2bf(x0.x);
        af[mi][1] = f2bf(x0.y);
        af[mi][2] = f2bf(x0.z);
        af[mi][3] = f2bf(x0.w);
        af[mi][4] = f2bf(x1.x);
        af[mi][5] = f2bf(x1.y);
        af[mi][6] = f2bf(x1.z);
        af[mi][7] = f2bf(x1.w);
      }
    }
    bf16x8 bfr[NF];
#pragma unroll
    for (int nf = 0; nf < NF; ++nf)
      bfr[nf] = ((const bf16x8*)Blds)[(ks * NPF + wn * NF + nf) * 64 + lane];
#pragma unroll
    for (int mi = 0; mi < 4; ++mi)
#pragma unroll
      for (int nf = 0; nf < NF; ++nf)
        acc[mi][nf] = __builtin_amdgcn_mfma_f32_16x16x32_bf16(af[mi], bfr[nf], acc[mi][nf], 0, 0, 0);
  }

#pragma unroll
  for (int mi = 0; mi < 4; ++mi) {
    int r0 = rowbase + mi * 16 + lgrp * 4;
#pragma unroll
    for (int nf = 0; nf < NF; ++nf) {
      int colc = (wn * NF + nf) * 16 + lrow;
#pragma unroll
      for (int rr = 0; rr < 4; ++rr) {
        int r = r0 + rr;
        if (r < n) H[(size_t)r * NTOT + colc] = f2bf(acc[mi][nf][rr]);
      }
    }
  }
}

// ---------------- fused CSR gather (bf16 in, 4-way edge-unrolled MLP) ----------------
// out[d] = act( h[d]*dinv[d]^2 + sum_e h[src]*nrm_e + b )

template <int CH, bool RELU, bool OUT_BF16>
__global__ __launch_bounds__(256) void gather_kernel(
    const short* __restrict__ h, const float* __restrict__ dinv, const float* __restrict__ b,
    const int* __restrict__ start, const int2* __restrict__ csr, void* __restrict__ outp,
    int n, int e_cnt) {
  constexpr int TPN = CH / 8;        // threads per node (8 ch each)
  constexpr int NPB = 256 / TPN;     // nodes per block
  const int tid = threadIdx.x;
  const int q = tid % TPN;
  const int g = tid / TPN;
  const int d = blockIdx.x * NPB + g;
  if (d >= n) return;
  const bf16x8* h8 = (const bf16x8*)h;
  float s = dinv[d];
  s = s * s;
  bf16x8 v = h8[(size_t)d * TPN + q];
  float a0[8], a1[8], a2[8], a3[8];
#pragma unroll
  for (int j = 0; j < 8; ++j) {
    a0[j] = bf2f(v[j]) * s + b[q * 8 + j];
    a1[j] = 0.f;
    a2[j] = 0.f;
    a3[j] = 0.f;
  }
  const int k0 = start[d];
  const int k1 = (d + 1 < n) ? start[d + 1] : e_cnt;
  int k = k0;
  for (; k + 4 <= k1; k += 4) {
    int2 e0 = csr[k];
    int2 e1 = csr[k + 1];
    int2 e2 = csr[k + 2];
    int2 e3 = csr[k + 3];
    bf16x8 h0 = h8[(size_t)e0.x * TPN + q];
    bf16x8 h1 = h8[(size_t)e1.x * TPN + q];
    bf16x8 h2 = h8[(size_t)e2.x * TPN + q];
    bf16x8 h3 = h8[(size_t)e3.x * TPN + q];
    float n0 = __int_as_float(e0.y);
    float n1 = __int_as_float(e1.y);
    float n2 = __int_as_float(e2.y);
    float n3 = __int_as_float(e3.y);
#pragma unroll
    for (int j = 0; j < 8; ++j) {
      a0[j] += bf2f(h0[j]) * n0;
      a1[j] += bf2f(h1[j]) * n1;
      a2[j] += bf2f(h2[j]) * n2;
      a3[j] += bf2f(h3[j]) * n3;
    }
  }
  for (; k < k1; ++k) {
    int2 e = csr[k];
    float nv = __int_as_float(e.y);
    bf16x8 hv = h8[(size_t)e.x * TPN + q];
#pragma unroll
    for (int j = 0; j < 8; ++j) a0[j] += bf2f(hv[j]) * nv;
  }
#pragma unroll
  for (int j = 0; j < 8; ++j) a0[j] += (a1[j] + a2[j]) + a3[j];
  if (RELU) {
#pragma unroll
    for (int j = 0; j < 8; ++j) a0[j] = fmaxf(a0[j], 0.f);
  }
  if (OUT_BF16) {
    bf16x8 ov;
#pragma unroll
    for (int j = 0; j < 8; ++j) ov[j] = f2bf(a0[j]);
    ((bf16x8*)outp)[(size_t)d * TPN + q] = ov;
  } else {
    float4* op = (float4*)outp + (size_t)d * (CH / 4) + q * 2;
    op[0] = make_float4(a0[0], a0[1], a0[2], a0[3]);
    op[1] = make_float4(a0[4], a0[5], a0[6], a0[7]);
  }
}

// ---------------- launch ----------------

extern "C" void kernel_launch(void* const* d_in, const int* in_sizes, int n_in,
                              void* d_out, int out_size, void* d_ws, size_t ws_size,
                              hipStream_t stream) {
  const float* x = (const float*)d_in[0];
  const int* ei = (const int*)d_in[1];
  const float* ew = (const float*)d_in[2];
  const float* W1 = (const float*)d_in[3];
  const float* b1 = (const float*)d_in[4];
  const float* W2 = (const float*)d_in[5];
  const float* b2 = (const float*)d_in[6];
  float* outp = (float*)d_out;

  const int N = NNODES, E = NEDGES;
  const int* rowp = ei;
  const int* colp = ei + E;

  // workspace carve-up (16B-aligned chunks first)
  char* wsb = (char*)d_ws;
  int2* binned = (int2*)wsb;    wsb += (size_t)NBUCK * MAXB * 8;   // 9.6 MB
  int2* csr = (int2*)wsb;       wsb += (size_t)E * 8;              // 6.4 MB
  short* h1 = (short*)wsb;      wsb += (size_t)N * 128 * 2;
  short* h1r = (short*)wsb;     wsb += (size_t)N * 128 * 2;
  short* h2 = (short*)wsb;      wsb += (size_t)N * 64 * 2;
  short* Wpk1 = (short*)wsb;    wsb += (size_t)256 * 128 * 2;      // 64 KB packed W1
  short* Wpk2 = (short*)wsb;    wsb += (size_t)128 * 64 * 2;       // 16 KB packed W2
  float* dinv = (float*)wsb;    wsb += (size_t)N * 4;
  int* start = (int*)wsb;       wsb += (size_t)N * 4;
  int* cntg = (int*)wsb;        wsb += (size_t)N * 4;
  int* gcur = (int*)wsb;        wsb += (size_t)NBUCK * 4;
  int* bbase = (int*)wsb;       wsb += (size_t)NBUCK * 4;

  // W pre-pack (tiny, independent of CSR build)
  packW_kernel<256, 128><<<16, 256, 0, stream>>>(W1, Wpk1);
  packW_kernel<128, 64><<<4, 256, 0, stream>>>(W2, Wpk2);

  // CSR build: bucketed counting sort (no per-edge global atomics)
  initcur_kernel<<<1, 256, 0, stream>>>(gcur);
  bin_kernel<<<(E + 2047) / 2048, 256, 0, stream>>>(rowp, colp, ew, gcur, binned, E);
  bdeg_kernel<<<NBUCK, 256, 0, stream>>>(binned, gcur, dinv, cntg, N);
  bscan_kernel<<<1, 256, 0, stream>>>(gcur, bbase);
  csrfill_kernel<<<NBUCK, 256, 0, stream>>>(binned, gcur, bbase, dinv, cntg, start, csr, N);

  // layer 1: MFMA GEMM (f32 A) -> bf16 h1; gather (+bias+relu) -> bf16 h1r
  mfma_gemm_kernel<256, 128, false><<<(N + 127) / 128, 256, 0, stream>>>(x, Wpk1, h1, N);
  gather_kernel<128, true, true><<<(N + 15) / 16, 256, 0, stream>>>(h1, dinv, b1, start, csr,
                                                                    h1r, N, E);

  // layer 2: MFMA GEMM (bf16 A) -> bf16 h2; gather (+bias) -> f32 out
  mfma_gemm_kernel<128, 64, true><<<(N + 127) / 128, 256, 0, stream>>>(h1r, Wpk2, h2, N);
  gather_kernel<64, false, false><<<(N + 31) / 32, 256, 0, stream>>>(h2, dinv, b2, start, csr,
                                                                     outp, N, E);
}

// Round 10
// 122.584 us; speedup vs baseline: 1.0473x; 1.0473x over previous
//
#include <hip/hip_runtime.h>
#include <hip/hip_bf16.h>
#include <math.h>

static constexpr int NNODES = 50000;
static constexpr int NEDGES = 800000;
static constexpr int NBUCK = (NNODES + 255) >> 8;  // 196 buckets of 256 dst nodes
static constexpr int MAXB = 6144;  // max edges/bucket (mean 4096 for uniform random)

typedef __attribute__((ext_vector_type(8))) short bf16x8;
typedef __attribute__((ext_vector_type(4))) float f32x4;

__device__ inline short f2bf(float f) {
  union { __hip_bfloat16 h; short s; } u;
  u.h = __float2bfloat16(f);
  return u.s;
}

__device__ inline float bf2f(short s) {
  union { unsigned int u; float f; } u;
  u.u = ((unsigned int)(unsigned short)s) << 16;
  return u.f;
}

// ---------------- setup: W pre-pack (fragment-major bf16) + gcur init ----------------
// Fragment f = kf*NPF + nfb; lane l holds W[kf*32 + (l>>4)*8 + i][nfb*16 + (l&15)], i=0..7.

template <int K, int NTOT>
__device__ inline void packW_body(const float* __restrict__ W, short* __restrict__ Wpk, int t) {
  constexpr int KF = K / 32;
  constexpr int NPF = NTOT / 16;
  if (t >= KF * NPF * 64) return;
  int f = t >> 6, l = t & 63;
  int kf = f / NPF, nfb = f % NPF;
  int col = nfb * 16 + (l & 15);
  int krow = kf * 32 + (l >> 4) * 8;
  bf16x8 bv;
#pragma unroll
  for (int i = 0; i < 8; ++i) bv[i] = f2bf(W[(size_t)(krow + i) * NTOT + col]);
  ((bf16x8*)Wpk)[t] = bv;
}

__global__ void setup_kernel(const float* __restrict__ W1, short* __restrict__ Wpk1,
                             const float* __restrict__ W2, short* __restrict__ Wpk2,
                             int* __restrict__ gcur) {
  const int bid = blockIdx.x, tid = threadIdx.x;
  if (bid < 16) {
    packW_body<256, 128>(W1, Wpk1, bid * 256 + tid);
  } else if (bid < 20) {
    packW_body<128, 64>(W2, Wpk2, (bid - 16) * 256 + tid);
  } else {
    if (tid < NBUCK) gcur[tid] = tid * MAXB;
  }
}

// ---------------- bucketed CSR build ----------------
// binned entry: int2 { (dst_local<<16) | src , float_bits(w) }  (src < 2^16, dl < 2^8)

// bin 2048 edges/WG into per-bucket regions. Per-WG LDS histogram -> ONE global
// atomic per (WG, bucket) -> contiguous run reservation -> direct int2 writes.
__global__ __launch_bounds__(256) void bin_kernel(const int* __restrict__ row,
                                                  const int* __restrict__ col,
                                                  const float* __restrict__ w,
                                                  int* __restrict__ gcur,
                                                  int2* __restrict__ binned, int e_cnt) {
  __shared__ int rcnt[NBUCK];
  __shared__ int rcur[NBUCK];
  __shared__ int gbase[NBUCK];
  const int tid = threadIdx.x;
  for (int b = tid; b < NBUCK; b += 256) {
    rcnt[b] = 0;
    rcur[b] = 0;
  }
  __syncthreads();
  const int base = blockIdx.x * 2048;
  int srcs[8], dsts[8];
  float ws_[8];
#pragma unroll
  for (int j = 0; j < 8; ++j) {
    int idx = base + tid + 256 * j;
    if (idx < e_cnt) {
      srcs[j] = row[idx];
      dsts[j] = col[idx];
      ws_[j] = w[idx];
      atomicAdd(&rcnt[dsts[j] >> 8], 1);
    } else {
      dsts[j] = -1;
    }
  }
  __syncthreads();
  for (int b = tid; b < NBUCK; b += 256)
    if (rcnt[b] > 0) gbase[b] = atomicAdd(&gcur[b], rcnt[b]);
  __syncthreads();
#pragma unroll
  for (int j = 0; j < 8; ++j) {
    if (dsts[j] >= 0) {
      int b = dsts[j] >> 8;
      int dl = dsts[j] & 255;
      int pos = gbase[b] + atomicAdd(&rcur[b], 1);
      binned[pos] = make_int2((dl << 16) | srcs[j], __float_as_int(ws_[j]));
    }
  }
}

// per-bucket deg (LDS f32 atomics) + cnt; block NBUCK does the bucket-base scan.
__global__ __launch_bounds__(256) void bdeg_kernel(const int2* __restrict__ binned,
                                                   const int* __restrict__ gcur,
                                                   float* __restrict__ dinv,
                                                   int* __restrict__ cntg,
                                                   int* __restrict__ bbase, int n) {
  const int b = blockIdx.x, tid = threadIdx.x;
  if (b == NBUCK) {  // exclusive scan of bucket counts
    __shared__ int buf[256];
    int v = (tid < NBUCK) ? gcur[tid] - tid * MAXB : 0;
    buf[tid] = v;
    __syncthreads();
    for (int off = 1; off < 256; off <<= 1) {
      int t = (tid >= off) ? buf[tid - off] : 0;
      __syncthreads();
      buf[tid] += t;
      __syncthreads();
    }
    if (tid < NBUCK) bbase[tid] = buf[tid] - v;
    return;
  }
  __shared__ float degf[256];
  __shared__ int cnt[256];
  degf[tid] = 0.f;
  cnt[tid] = 0;
  __syncthreads();
  const int bcnt = gcur[b] - b * MAXB;
  const int2* bp = binned + (size_t)b * MAXB;
  for (int i = tid; i < bcnt; i += 256) {
    int2 e = bp[i];
    int dl = (e.x >> 16) & 255;
    atomicAdd(&degf[dl], __int_as_float(e.y));
    atomicAdd(&cnt[dl], 1);
  }
  __syncthreads();
  int node = b * 256 + tid;
  if (node < n) {
    dinv[node] = 1.0f / sqrtf(degf[tid] + 1.0f);  // self-loop weight 1.0
    cntg[node] = cnt[tid];
  }
}

// per-bucket: local scan -> start[]; norm + CSR fill via LDS cursors.
__global__ __launch_bounds__(256) void csrfill_kernel(
    const int2* __restrict__ binned, const int* __restrict__ gcur,
    const int* __restrict__ bbase, const float* __restrict__ dinv,
    const int* __restrict__ cntg, int* __restrict__ start, int2* __restrict__ csr, int n) {
  __shared__ float dvL[256];
  __shared__ int cur[256];
  __shared__ int buf[256];
  const int b = blockIdx.x, tid = threadIdx.x;
  const int node = b * 256 + tid;
  int c = (node < n) ? cntg[node] : 0;
  dvL[tid] = (node < n) ? dinv[node] : 0.f;
  buf[tid] = c;
  __syncthreads();
  for (int off = 1; off < 256; off <<= 1) {
    int t = (tid >= off) ? buf[tid - off] : 0;
    __syncthreads();
    buf[tid] += t;
    __syncthreads();
  }
  int localstart = buf[tid] - c;
  const int gb = bbase[b];
  if (node < n) start[node] = gb + localstart;
  cur[tid] = localstart;
  __syncthreads();
  const int bcnt = gcur[b] - b * MAXB;
  const int2* bp = binned + (size_t)b * MAXB;
  for (int i = tid; i < bcnt; i += 256) {
    int2 e = bp[i];
    int src = e.x & 0xFFFF;
    int dl = (e.x >> 16) & 255;
    float nrm = dinv[src] * __int_as_float(e.y) * dvL[dl];
    int pos = gb + atomicAdd(&cur[dl], 1);
    csr[pos] = make_int2(src, __float_as_int(nrm));
  }
}

// ---------------- bf16 MFMA GEMM: 1 wave/block, 16 rows/wave ----------------
// Grid = n/16 single-wave blocks (max wave parallelism for latency hiding).
// B fragments read directly from pre-packed global Wpk (L2-hot, coalesced 1KB/frag).
// D layout col=lane&15, row=(lane>>4)*4+reg [m89-verified].

template <int K, int NTOT, bool A_BF16>
__global__ __launch_bounds__(64, 4) void mfma_gemm_kernel(const void* __restrict__ Av,
                                                          const short* __restrict__ Wpk,
                                                          short* __restrict__ H, int n) {
  constexpr int KF = K / 32;
  constexpr int NF = NTOT / 16;  // wave covers all N columns
  const int lane = threadIdx.x;
  const int lrow = lane & 15;
  const int lgrp = lane >> 4;
  const int rowbase = blockIdx.x * 16;
  const int nmax = n - 1;
  int r = rowbase + lrow;
  r = r > nmax ? nmax : r;
  const bf16x8* Wf = (const bf16x8*)Wpk;
  f32x4 acc[NF] = {};

#pragma unroll
  for (int ks = 0; ks < KF; ++ks) {
    bf16x8 a;
    if (A_BF16) {
      const short* X = (const short*)Av;
      a = *(const bf16x8*)(X + (size_t)r * K + ks * 32 + lgrp * 8);
    } else {
      const float* X = (const float*)Av;
      const float* xp = X + (size_t)r * K + ks * 32 + lgrp * 8;
      float4 x0 = *(const float4*)xp;
      float4 x1 = *(const float4*)(xp + 4);
      a[0] = f2bf(x0.x);
      a[1] = f2bf(x0.y);
      a[2] = f2bf(x0.z);
      a[3] = f2bf(x0.w);
      a[4] = f2bf(x1.x);
      a[5] = f2bf(x1.y);
      a[6] = f2bf(x1.z);
      a[7] = f2bf(x1.w);
    }
#pragma unroll
    for (int nf = 0; nf < NF; ++nf) {
      bf16x8 bfr = Wf[(ks * NF + nf) * 64 + lane];
      acc[nf] = __builtin_amdgcn_mfma_f32_16x16x32_bf16(a, bfr, acc[nf], 0, 0, 0);
    }
  }

#pragma unroll
  for (int nf = 0; nf < NF; ++nf) {
    int colc = nf * 16 + lrow;
#pragma unroll
    for (int rr = 0; rr < 4; ++rr) {
      int r2 = rowbase + lgrp * 4 + rr;
      if (r2 < n) H[(size_t)r2 * NTOT + colc] = f2bf(acc[nf][rr]);
    }
  }
}

// ---------------- fused CSR gather (bf16 in, 4-way edge-unrolled MLP) ----------------
// out[d] = act( h[d]*dinv[d]^2 + sum_e h[src]*nrm_e + b )

template <int CH, bool RELU, bool OUT_BF16>
__global__ __launch_bounds__(256) void gather_kernel(
    const short* __restrict__ h, const float* __restrict__ dinv, const float* __restrict__ b,
    const int* __restrict__ start, const int2* __restrict__ csr, void* __restrict__ outp,
    int n, int e_cnt) {
  constexpr int TPN = CH / 8;        // threads per node (8 ch each)
  constexpr int NPB = 256 / TPN;     // nodes per block
  const int tid = threadIdx.x;
  const int q = tid % TPN;
  const int g = tid / TPN;
  const int d = blockIdx.x * NPB + g;
  if (d >= n) return;
  const bf16x8* h8 = (const bf16x8*)h;
  float s = dinv[d];
  s = s * s;
  bf16x8 v = h8[(size_t)d * TPN + q];
  float a0[8], a1[8], a2[8], a3[8];
#pragma unroll
  for (int j = 0; j < 8; ++j) {
    a0[j] = bf2f(v[j]) * s + b[q * 8 + j];
    a1[j] = 0.f;
    a2[j] = 0.f;
    a3[j] = 0.f;
  }
  const int k0 = start[d];
  const int k1 = (d + 1 < n) ? start[d + 1] : e_cnt;
  int k = k0;
  for (; k + 4 <= k1; k += 4) {
    int2 e0 = csr[k];
    int2 e1 = csr[k + 1];
    int2 e2 = csr[k + 2];
    int2 e3 = csr[k + 3];
    bf16x8 h0 = h8[(size_t)e0.x * TPN + q];
    bf16x8 h1 = h8[(size_t)e1.x * TPN + q];
    bf16x8 h2 = h8[(size_t)e2.x * TPN + q];
    bf16x8 h3 = h8[(size_t)e3.x * TPN + q];
    float n0 = __int_as_float(e0.y);
    float n1 = __int_as_float(e1.y);
    float n2 = __int_as_float(e2.y);
    float n3 = __int_as_float(e3.y);
#pragma unroll
    for (int j = 0; j < 8; ++j) {
      a0[j] += bf2f(h0[j]) * n0;
      a1[j] += bf2f(h1[j]) * n1;
      a2[j] += bf2f(h2[j]) * n2;
      a3[j] += bf2f(h3[j]) * n3;
    }
  }
  for (; k < k1; ++k) {
    int2 e = csr[k];
    float nv = __int_as_float(e.y);
    bf16x8 hv = h8[(size_t)e.x * TPN + q];
#pragma unroll
    for (int j = 0; j < 8; ++j) a0[j] += bf2f(hv[j]) * nv;
  }
#pragma unroll
  for (int j = 0; j < 8; ++j) a0[j] += (a1[j] + a2[j]) + a3[j];
  if (RELU) {
#pragma unroll
    for (int j = 0; j < 8; ++j) a0[j] = fmaxf(a0[j], 0.f);
  }
  if (OUT_BF16) {
    bf16x8 ov;
#pragma unroll
    for (int j = 0; j < 8; ++j) ov[j] = f2bf(a0[j]);
    ((bf16x8*)outp)[(size_t)d * TPN + q] = ov;
  } else {
    float4* op = (float4*)outp + (size_t)d * (CH / 4) + q * 2;
    op[0] = make_float4(a0[0], a0[1], a0[2], a0[3]);
    op[1] = make_float4(a0[4], a0[5], a0[6], a0[7]);
  }
}

// ---------------- launch ----------------

extern "C" void kernel_launch(void* const* d_in, const int* in_sizes, int n_in,
                              void* d_out, int out_size, void* d_ws, size_t ws_size,
                              hipStream_t stream) {
  const float* x = (const float*)d_in[0];
  const int* ei = (const int*)d_in[1];
  const float* ew = (const float*)d_in[2];
  const float* W1 = (const float*)d_in[3];
  const float* b1 = (const float*)d_in[4];
  const float* W2 = (const float*)d_in[5];
  const float* b2 = (const float*)d_in[6];
  float* outp = (float*)d_out;

  const int N = NNODES, E = NEDGES;
  const int* rowp = ei;
  const int* colp = ei + E;

  // workspace carve-up (16B-aligned chunks first)
  char* wsb = (char*)d_ws;
  int2* binned = (int2*)wsb;    wsb += (size_t)NBUCK * MAXB * 8;   // 9.6 MB
  int2* csr = (int2*)wsb;       wsb += (size_t)E * 8;              // 6.4 MB
  short* h1 = (short*)wsb;      wsb += (size_t)N * 128 * 2;
  short* h1r = (short*)wsb;     wsb += (size_t)N * 128 * 2;
  short* h2 = (short*)wsb;      wsb += (size_t)N * 64 * 2;
  short* Wpk1 = (short*)wsb;    wsb += (size_t)256 * 128 * 2;      // 64 KB packed W1
  short* Wpk2 = (short*)wsb;    wsb += (size_t)128 * 64 * 2;       // 16 KB packed W2
  float* dinv = (float*)wsb;    wsb += (size_t)N * 4;
  int* start = (int*)wsb;       wsb += (size_t)N * 4;
  int* cntg = (int*)wsb;        wsb += (size_t)N * 4;
  int* gcur = (int*)wsb;        wsb += (size_t)NBUCK * 4;
  int* bbase = (int*)wsb;       wsb += (size_t)NBUCK * 4;

  // setup: pack W1/W2 + init gcur (one launch)
  setup_kernel<<<21, 256, 0, stream>>>(W1, Wpk1, W2, Wpk2, gcur);

  // CSR build: bucketed counting sort (no per-edge global atomics)
  bin_kernel<<<(E + 2047) / 2048, 256, 0, stream>>>(rowp, colp, ew, gcur, binned, E);
  bdeg_kernel<<<NBUCK + 1, 256, 0, stream>>>(binned, gcur, dinv, cntg, bbase, N);
  csrfill_kernel<<<NBUCK, 256, 0, stream>>>(binned, gcur, bbase, dinv, cntg, start, csr, N);

  // layer 1: MFMA GEMM (f32 A) -> bf16 h1; gather (+bias+relu) -> bf16 h1r
  mfma_gemm_kernel<256, 128, false><<<(N + 15) / 16, 64, 0, stream>>>(x, Wpk1, h1, N);
  gather_kernel<128, true, true><<<(N + 15) / 16, 256, 0, stream>>>(h1, dinv, b1, start, csr,
                                                                    h1r, N, E);

  // layer 2: MFMA GEMM (bf16 A) -> bf16 h2; gather (+bias) -> f32 out
  mfma_gemm_kernel<128, 64, true><<<(N + 15) / 16, 64, 0, stream>>>(h1r, Wpk2, h2, N);
  gather_kernel<64, false, false><<<(N + 31) / 32, 256, 0, stream>>>(h2, dinv, b2, start, csr,
                                                                     outp, N, E);
}